// Round 11
// baseline (303.706 us; speedup 1.0000x reference)
//
#include <hip/hip_runtime.h>
#include <hip/hip_bf16.h>
#include <math.h>

// ---------------- problem constants ----------------
#define A_    32
#define B_    32
#define PS    16
#define KK_   9
#define KKA_  288      // KK_*A_
#define OH_   7
#define L_    49
#define NB    4
#define NSITE 196      // NB*L_

#define LAM1 5.0e-4f        // 0.01*(1-0.95^1)
#define LAM2 9.75e-4f       // 0.01*(1-0.95^2)
#define LAM3 1.42625e-3f    // 0.01*(1-0.95^3)
#define LOG_LN2PI 0.6086775903077413f  // log(log(2*pi))

typedef _Float16 half2v __attribute__((ext_vector_type(2)));
typedef short    short8 __attribute__((ext_vector_type(8)));   // 8 bf16 (4 VGPRs)
typedef float    floatx4 __attribute__((ext_vector_type(4)));

static __device__ __forceinline__ float san(float x, float lo, float hi){
    return fminf(fmaxf(x, lo), hi);
}

static __device__ __forceinline__ float dot2acc(half2v a, half2v b, float c){
#if __has_builtin(__builtin_amdgcn_fdot2)
    return __builtin_amdgcn_fdot2(a, b, c, false);
#else
    return c + (float)a.x*(float)b.x + (float)a.y*(float)b.y;
#endif
}

static __device__ __forceinline__ void sched_fence(){
#if __has_builtin(__builtin_amdgcn_sched_barrier)
    __builtin_amdgcn_sched_barrier(0);
#else
    asm volatile("" ::: "memory");
#endif
}

// ================= K1: fused prep =================
// blocks [0, nc): c'_p filter -> parity-split bf16 hi/lo tables (FIRST: serial dep of stageB)
// blocks [nc, nc+nx): unfold pose -> Xt (bf16, transposed [col][j])
// cpr_ext[x] = c'_p[(576 - x) mod 288]; A[i][k] = c'[(i-k) mod 288] = cpr_ext[288 + k - i]
__global__ void k_prep(const float* __restrict__ fw, const float* __restrict__ pose,
                       ushort* __restrict__ cpr, float* __restrict__ csum,
                       __hip_bfloat16* __restrict__ Xt, int n0, int cols, int nc)
{
    if ((int)blockIdx.x < nc){
        int id = (int)blockIdx.x*256 + threadIdx.x;
        if (id >= 16*288) return;
        int p = id / 288, m = id % 288;
        // c2r irfft ignores imag of DC/Nyquist bins; ortho norms cancel to 1/N
        float acc = fw[(0*16 + p)*2 + 0];
        for (int k = 1; k <= 143; ++k){
            float re = fw[(k*16 + p)*2 + 0];
            float im = fw[(k*16 + p)*2 + 1];
            int km = (k*m) % 288;
            float ang = 0.021816615649929116f * (float)km;  // 2*pi/288
            float s, c; __sincosf(ang, &s, &c);             // err ~1e-7 << bf16 table quant
            acc += 2.0f*(re*c - im*s);
        }
        float re144 = fw[(144*16 + p)*2 + 0];
        acc += re144 * ((m & 1) ? -1.0f : 1.0f);
        float cv = acc * (1.0f/288.0f);
        if (m == 0) cv += 1.0f;                            // + identity (residual)
        cv = san(cv, -1e4f, 1e4f);

        __hip_bfloat16 hb = __float2bfloat16(cv);
        float hif = __bfloat162float(hb);
        __hip_bfloat16 lb = __float2bfloat16(cv - hif);
        ushort hi = *(ushort*)&hb, lo = *(ushort*)&lb;

        ushort* c0h = cpr + p*592;
        ushort* c1h = cpr + 16*592   + p*592;
        ushort* c0l = cpr + 16*592*2 + p*592;
        ushort* c1l = cpr + 16*592*3 + p*592;
        int x1 = 288 - m;                       // covers cpr0[1..288], cpr1[0..287]
        c0h[x1] = hi;  c0l[x1] = lo;
        c1h[x1-1] = hi; c1l[x1-1] = lo;
        if (m >= 1){                            // covers cpr0[289..575], cpr1[288..574]
            int x2 = 576 - m;
            c0h[x2] = hi;  c0l[x2] = lo;
            c1h[x2-1] = hi; c1l[x2-1] = lo;
        } else {                                // cpr0[0] = cpr_ext[0] = c'[0]
            c0h[0] = hi; c0l[0] = lo;
            csum[p] = san(1.0f + fw[(0*16 + p)*2 + 0], -1e4f, 1e4f);
        }
        return;
    }
    int id = ((int)blockIdx.x - nc)*256 + threadIdx.x;
    if (id >= cols*KKA_) return;
    int c = id / KKA_, j = id % KKA_;
    int n = n0 + (c >> 4), q = c & 15;
    int bs = n / L_, l = n % L_, oy = l / OH_, ox = l % OH_;
    int kk = j >> 5, a = j & 31;
    int y = oy*2 - 1 + kk/3, x = ox*2 - 1 + kk%3;
    float v = 0.f;
    if ((unsigned)y < 14u && (unsigned)x < 14u)
        v = pose[((bs*(A_*PS) + a*PS + q)*14 + y)*14 + x];
    Xt[id] = __float2bfloat16(san(v, -1e4f, 1e4f));
}

// ================= K3: U_p = (I + C_p) @ X via bf16 split-MFMA =================
// block: 48 i x 64 cols for one p; 4 waves, wave w owns 16-col slice, 3 i-subtiles.
__launch_bounds__(256)
__global__ void k_stageB(const ushort* __restrict__ cpr, const __hip_bfloat16* __restrict__ Xt,
                         _Float16* __restrict__ U, int cols, int ns)
{
    const int bx = blockIdx.x, by = blockIdx.y, p = blockIdx.z;
    const int t = threadIdx.x;
    const int w = t >> 6, lane = t & 63;
    const int mn = lane & 15, quad = lane >> 4;
    const int i0 = by*48;
    const int col = bx*64 + w*16 + mn;
    const int colc = (col < cols) ? col : (cols - 1);

    const ushort* c0h = cpr + p*592;
    const ushort* c1h = cpr + 16*592   + p*592;
    const ushort* c0l = cpr + 16*592*2 + p*592;
    const ushort* c1l = cpr + 16*592*3 + p*592;

    floatx4 acc[3] = {{0,0,0,0},{0,0,0,0},{0,0,0,0}};
    #pragma unroll                                  // compile-time offsets, deep load pipelining
    for (int k0 = 0; k0 < 288; k0 += 32){
        short8 bfrag = *(const short8*)&Xt[colc*KKA_ + k0 + quad*8];
        #pragma unroll
        for (int s = 0; s < 3; ++s){
            // A[m][k] = cpr_ext[288 + k - i], i = i0+s*16+mn, k = k0+quad*8+jj
            int o = 288 + k0 + quad*8 - (i0 + s*16 + mn);
            int sel = o & 1;                 // parity -> pick shifted table, stay 4B-aligned
            int off = o - sel;
            const ushort* bh = sel ? c1h : c0h;
            const ushort* bl = sel ? c1l : c0l;
            short8 ah = *(const short8*)&bh[off];
            short8 al = *(const short8*)&bl[off];
            acc[s] = __builtin_amdgcn_mfma_f32_16x16x32_bf16(ah, bfrag, acc[s], 0, 0, 0);
            acc[s] = __builtin_amdgcn_mfma_f32_16x16x32_bf16(al, bfrag, acc[s], 0, 0, 0);
        }
    }
    if (col < cols){
        const int nn = col >> 4, q0 = col & 15;      // local site, q
        #pragma unroll
        for (int s = 0; s < 3; ++s){
            #pragma unroll
            for (int r = 0; r < 4; ++r){
                int i = i0 + s*16 + quad*4 + r;      // D: row = quad*4 + reg
                U[(i*ns + nn)*256 + p*16 + q0] = (_Float16)acc[s][r];
            }
        }
    }
}

// ================= K4: v in LDS (i<144) / RECOMPUTED (i>=144) + 3 fused EM iters =================
// Rounds 6-10: storing all of v per-thread spills regardless of attributes.
// Resolution: v for i<144 lives in LDS (lane-indexed, conflict-free); v for
// i>=144 is RECOMPUTED from L2-resident U inside iterations 2-3 (24 packed
// pairs in registers per 48-chunk). Register demand ~90 -> spills impossible.
// launch_bounds(512,1): if arg-2 is blocks/CU (CUDA semantics), (512,2) was
// silently capping VGPRs at 128 - this lifts the cap to 256 either way.
__launch_bounds__(512, 1)
__global__ void
k_em(const _Float16* __restrict__ U, const float* __restrict__ a_in,
     const float* __restrict__ mpw, const float* __restrict__ mpb,
     const float* __restrict__ csum,
     const float* __restrict__ beta_u, const float* __restrict__ beta_a,
     int n0, int ns, float* __restrict__ out)
{
    const int nl = blockIdx.x;          // local site in group
    const int n  = n0 + nl;             // global site
    const int t = threadIdx.x;          // 512
    const int Bc = t >> 4, p = t & 15;  // thread = (Bc, p)
    const int bs = n / L_, l = n % L_;

    __shared__ uint  v_lds[72][512];    // i-pairs for i in [0,144): [ip][t], thread-private
    __shared__ float d_s[48][33];       // distances, then r in-place
    __shared__ float a_s[KKA_];
    __shared__ float cst[32];

    // unfold this site's activation row
    for (int j = t; j < KKA_; j += 512){
        int kk = j >> 5, a = j & 31;
        int oy = l / OH_, ox = l % OH_;
        int y = oy*2 - 1 + kk/3, x = ox*2 - 1 + kk%3;
        float v = 0.f;
        if ((unsigned)y < 14u && (unsigned)x < 14u)
            v = a_in[((bs*A_ + a)*14 + y)*14 + x];
        a_s[j] = san(v, 0.f, 1e4f);
    }
    // per-thread weight row as packed fp16
    half2v w_h[8];
    #pragma unroll
    for (int k = 0; k < 8; ++k){
        w_h[k].x = (_Float16)mpw[t*16 + 2*k];
        w_h[k].y = (_Float16)mpw[t*16 + 2*k + 1];
    }
    const float vb = mpb[t] * csum[p];  // bias pushed through the filter
    const float bu = beta_u[Bc];
    const float ba = beta_a[Bc];
    __syncthreads();                    // a_s ready

    float S0tot = 0.f;
    for (int j = 0; j < KKA_; ++j) S0tot += a_s[j];   // broadcast reads

    // U fragment base for this thread: U[(i*ns+nl)*256 + p*16 + q]
    const _Float16* Up = U + nl*256 + p*16;
    const int istr = ns*256;

    float S1 = 0.f, S2 = 0.f;

    // ---- phase 1a: i in [144,288): moments ONLY (v discarded, recomputed later) ----
    #pragma unroll
    for (int g = 0; g < 18; ++g){                    // 4 pairs per fence group
        #pragma unroll
        for (int k2 = 0; k2 < 4; ++k2){
            const int i0 = 144 + (g*4 + k2)*2;
            union { uint4 u4; half2v h2[4]; } A0, A1, B0, B1;
            A0.u4 = *(const uint4*)&Up[i0*istr];
            A1.u4 = *(const uint4*)&Up[i0*istr + 8];
            B0.u4 = *(const uint4*)&Up[(i0+1)*istr];
            B1.u4 = *(const uint4*)&Up[(i0+1)*istr + 8];
            float v0 = vb, v1 = vb;
            #pragma unroll
            for (int m = 0; m < 4; ++m){
                v0 = dot2acc(A0.h2[m], w_h[m],   v0);
                v0 = dot2acc(A1.h2[m], w_h[4+m], v0);
                v1 = dot2acc(B0.h2[m], w_h[m],   v1);
                v1 = dot2acc(B1.h2[m], w_h[4+m], v1);
            }
            const float a0 = a_s[i0], a1 = a_s[i0+1];
            S1 += a0*v0 + a1*v1;
            S2 += a0*v0*v0 + a1*v1*v1;
        }
        sched_fence();                               // cap in-flight loads
    }

    // ---- phase 1b: i in [0,144): v -> LDS + moments ----
    for (int ch = 0; ch < 9; ++ch){
        #pragma unroll
        for (int k = 0; k < 8; ++k){
            const int i0 = ch*16 + 2*k;
            union { uint4 u4; half2v h2[4]; } A0, A1, B0, B1;
            A0.u4 = *(const uint4*)&Up[i0*istr];
            A1.u4 = *(const uint4*)&Up[i0*istr + 8];
            B0.u4 = *(const uint4*)&Up[(i0+1)*istr];
            B1.u4 = *(const uint4*)&Up[(i0+1)*istr + 8];
            float v0 = vb, v1 = vb;
            #pragma unroll
            for (int m = 0; m < 4; ++m){
                v0 = dot2acc(A0.h2[m], w_h[m],   v0);
                v0 = dot2acc(A1.h2[m], w_h[4+m], v0);
                v1 = dot2acc(B0.h2[m], w_h[m],   v1);
                v1 = dot2acc(B1.h2[m], w_h[4+m], v1);
            }
            const float a0 = a_s[i0], a1 = a_s[i0+1];
            S1 += a0*v0 + a1*v1;
            S2 += a0*v0*v0 + a1*v1*v1;
            union { half2v h; uint u; } cv;
            cv.h.x = (_Float16)v0; cv.h.y = (_Float16)v1;
            v_lds[ch*8 + k][t] = cv.u;
        }
    }

    // iter-1 m-step (r = 1/32 exactly); mu/i2s live in registers
    float mu_r, i2s_r;
    {
        const float rs  = S0tot * (1.0f/32.0f);
        const float inv = 1.0f / (rs + 1e-12f);
        const float S1r = S1 * (1.0f/32.0f), S2r = S2 * (1.0f/32.0f);
        mu_r = S1r * inv;
        const float sg  = fmaxf((S2r - 2.f*mu_r*S1r + mu_r*mu_r*rs) * inv, 0.f) + 1e-12f;
        i2s_r = 0.5f / sg;
        const float lg  = logf(sg);
        float cs = (bu + 0.5f*lg) * rs;
        float ls = lg + LOG_LN2PI;
        #pragma unroll
        for (int m = 1; m < 16; m <<= 1){ cs += __shfl_xor(cs, m, 16); ls += __shfl_xor(ls, m, 16); }
        const float aout = san(1.f/(1.f + expf(-LAM1*(ba - cs))), 1e-30f, 1.f);
        if (p == 0) cst[Bc] = logf(aout) - 0.5f*ls;
    }
    __syncthreads();

    // ---- iterations 2,3: 48-i chunks, 2 barriers each ----
    const int b0 = p & 1, b1 = (p>>1)&1, b2 = (p>>2)&1, b3 = (p>>3)&1;
    float muF = 0.f, aF = 0.f;
    for (int it = 0; it < 2; ++it){
        const float lam = it ? LAM3 : LAM2;
        float T0 = 0.f, T1 = 0.f, T2 = 0.f;

        #pragma unroll
        for (int ch = 0; ch < 6; ++ch){              // ch<3: LDS half; ch>=3: recompute half
            half2v vcache[24];
            if (ch >= 3){
                // recompute 24 pairs from L2-warm U (same addresses as phase 1a)
                #pragma unroll
                for (int gs = 0; gs < 12; ++gs){     // 2 pairs per fence group
                    #pragma unroll
                    for (int k2 = 0; k2 < 2; ++k2){
                        const int s = gs*2 + k2;
                        const int i0 = (ch*24 + s)*2;    // 144..286
                        union { uint4 u4; half2v h2[4]; } A0, A1, B0, B1;
                        A0.u4 = *(const uint4*)&Up[i0*istr];
                        A1.u4 = *(const uint4*)&Up[i0*istr + 8];
                        B0.u4 = *(const uint4*)&Up[(i0+1)*istr];
                        B1.u4 = *(const uint4*)&Up[(i0+1)*istr + 8];
                        float v0 = vb, v1 = vb;
                        #pragma unroll
                        for (int m = 0; m < 4; ++m){
                            v0 = dot2acc(A0.h2[m], w_h[m],   v0);
                            v0 = dot2acc(A1.h2[m], w_h[4+m], v0);
                            v1 = dot2acc(B0.h2[m], w_h[m],   v1);
                            v1 = dot2acc(B1.h2[m], w_h[4+m], v1);
                        }
                        half2v vh; vh.x = (_Float16)v0; vh.y = (_Float16)v1;
                        vcache[s] = vh;
                    }
                    sched_fence();
                }
            } else {
                #pragma unroll
                for (int s = 0; s < 24; ++s){
                    union { uint u; half2v h; } cv; cv.u = v_lds[ch*24 + s][t];
                    vcache[s] = cv.h;
                }
            }
            // (a) distances for 3 independent 16-i groups (ILP over g)
            #pragma unroll
            for (int g = 0; g < 3; ++g){
                float e1[8], e2[4], e3[2], dfin;
                #pragma unroll
                for (int s = 0; s < 8; ++s){
                    half2v vh = vcache[g*8 + s];
                    float v0 = (float)vh.x, v1 = (float)vh.y;
                    float d0 = v0 - mu_r, d1 = v1 - mu_r;
                    float ea = d0*d0*i2s_r, eb = d1*d1*i2s_r;
                    float aown  = b0 ? eb : ea;
                    float asend = b0 ? ea : eb;
                    e1[s] = aown + __shfl_xor(asend, 1);
                }
                #pragma unroll
                for (int s = 0; s < 4; ++s){
                    float aown  = b1 ? e1[2*s+1] : e1[2*s];
                    float asend = b1 ? e1[2*s]   : e1[2*s+1];
                    e2[s] = aown + __shfl_xor(asend, 2);
                }
                #pragma unroll
                for (int s = 0; s < 2; ++s){
                    float aown  = b2 ? e2[2*s+1] : e2[2*s];
                    float asend = b2 ? e2[2*s]   : e2[2*s+1];
                    e3[s] = aown + __shfl_xor(asend, 4);
                }
                {
                    float aown  = b3 ? e3[1] : e3[0];
                    float asend = b3 ? e3[0] : e3[1];
                    dfin = aown + __shfl_xor(asend, 8);
                }
                d_s[g*16 + p][Bc] = dfin;            // lane p holds d(i = ch*48+g*16+p)
            }
            __syncthreads();                         // (1) d_s ready (cross-wave)
            // (b) softmax over B, 3 independent rows per thread; r in place
            {
                const int isub = t >> 5, Bce = t & 31;
                #pragma unroll
                for (int rr = 0; rr < 3; ++rr){
                    const int row = rr*16 + isub;
                    float lnap = cst[Bce] - d_s[row][Bce];
                    float mx = lnap;
                    #pragma unroll
                    for (int m = 16; m >= 1; m >>= 1) mx = fmaxf(mx, __shfl_xor(mx, m));
                    float ex = expf(lnap - mx);
                    float sm = ex;
                    #pragma unroll
                    for (int m = 16; m >= 1; m >>= 1) sm += __shfl_xor(sm, m);
                    d_s[row][Bce] = (ex / sm) * a_s[ch*48 + row];
                }
            }
            __syncthreads();                         // (2) r ready (cross-wave)
            // (c) accumulate 24 pairs from vcache; next chunk's d_s writes are
            //     column-private to this wave -> no trailing barrier
            #pragma unroll
            for (int s = 0; s < 24; ++s){
                half2v vh = vcache[s];
                float v0 = (float)vh.x, v1 = (float)vh.y;
                float r0 = d_s[2*s][Bc], r1 = d_s[2*s+1][Bc];
                T0 += r0 + r1;
                T1 += r0*v0 + r1*v1;
                T2 += r0*v0*v0 + r1*v1*v1;
            }
        }
        // m-step
        const float inv = 1.f/(T0 + 1e-12f);
        const float mu  = T1 * inv;
        const float sg  = fmaxf((T2 - 2.f*mu*T1 + mu*mu*T0) * inv, 0.f) + 1e-12f;
        const float lg  = logf(sg);
        float cs = (bu + 0.5f*lg) * T0;
        float ls = lg + LOG_LN2PI;
        #pragma unroll
        for (int m = 1; m < 16; m <<= 1){ cs += __shfl_xor(cs, m, 16); ls += __shfl_xor(ls, m, 16); }
        const float aout = san(1.f/(1.f + expf(-lam*(ba - cs))), 1e-30f, 1.f);
        if (it == 0){
            mu_r = mu; i2s_r = 0.5f/sg;
            if (p == 0) cst[Bc] = logf(aout) - 0.5f*ls;
            __syncthreads();                         // cst visible; also orders d_s reuse
        } else { muF = mu; aF = aout; }
    }

    // ---- outputs (fp32): [a_fin 4*32*49][pose_out 4*512*49] ----
    if (p == 0) out[bs*(B_*L_) + Bc*L_ + l] = san(aF, 0.f, 1.f);
    out[6272 + (bs*512 + t)*L_ + l] = san(muF, -1e4f, 1e4f);
}

// ================= launch =================
extern "C" void kernel_launch(void* const* d_in, const int* in_sizes, int n_in,
                              void* d_out, int out_size, void* d_ws, size_t ws_size,
                              hipStream_t stream)
{
    // ALL device tensors are float32 (reference is jnp.float32 end-to-end).
    const float* a_in   = (const float*)d_in[0];
    const float* pose   = (const float*)d_in[1];
    const float* mpw    = (const float*)d_in[2];
    const float* mpb    = (const float*)d_in[3];
    const float* fw     = (const float*)d_in[4];
    // d_in[5..8] (ln_g, ln_b, spat_w, spat_bias) are provably dead: softmax over B of a
    // B-independent gate is exactly 1/B regardless of their values.
    const float* beta_u = (const float*)d_in[9];
    const float* beta_a = (const float*)d_in[10];
    float* out = (float*)d_out;

    // ---- ws layout (byte offsets) ----
    // csum [16] f32        @ 0      (64 B)
    // cpr  4x[16][592] u16 @ 256    (75776 B)
    // Xt   [cols][288] bf16 @ 76288 (576*cols B)
    // Ug   [288*ns*256] f16 @ 76288 + 9216*ns (147456*ns B)
    char* base = (char*)d_ws;
    float*  csum = (float*)(base + 0);
    ushort* cpr  = (ushort*)(base + 256);

    const int opts[] = {196, 98, 49, 28, 14, 7, 4, 2, 1};
    int ns = 1;
    for (int oi = 0; oi < 9; ++oi){
        size_t need = 76288u + (size_t)156672u * (size_t)opts[oi];
        if (need <= ws_size){ ns = opts[oi]; break; }
    }
    const int G = NSITE / ns;
    const int cols = ns * PS;
    __hip_bfloat16* Xt = (__hip_bfloat16*)(base + 76288);
    _Float16*       Ug = (_Float16*)(base + 76288 + (size_t)9216*ns);

    for (int g = 0; g < G; ++g){
        const int n0 = g * ns;
        const int nx = (cols*KKA_ + 255)/256;
        const int nc = (g == 0) ? 18 : 0;    // cpr blocks first (serial dep of stageB)
        k_prep  <<<nx + nc, 256, 0, stream>>>(fw, pose, cpr, csum, Xt, n0, cols, nc);
        k_stageB<<<dim3((cols + 63)/64, 6, 16), 256, 0, stream>>>(cpr, Xt, Ug, cols, ns);
        k_em    <<<ns, 512, 0, stream>>>(Ug, a_in, mpw, mpb, csum, beta_u, beta_a, n0, ns, out);
    }
}

// Round 12
// 252.727 us; speedup vs baseline: 1.2017x; 1.2017x over previous
//
#include <hip/hip_runtime.h>
#include <hip/hip_bf16.h>
#include <math.h>

// ---------------- problem constants ----------------
#define A_    32
#define B_    32
#define PS    16
#define KK_   9
#define KKA_  288      // KK_*A_
#define OH_   7
#define L_    49
#define NB    4
#define NSITE 196      // NB*L_
#define NCOLS 3136     // NSITE*16

#define LAM1 5.0e-4f        // 0.01*(1-0.95^1)
#define LAM2 9.75e-4f       // 0.01*(1-0.95^2)
#define LAM3 1.42625e-3f    // 0.01*(1-0.95^3)
#define LOG_LN2PI 0.6086775903077413f  // log(log(2*pi))

typedef _Float16 half2v __attribute__((ext_vector_type(2)));
typedef short    short8 __attribute__((ext_vector_type(8)));   // 8 bf16 (4 VGPRs)
typedef float    floatx4 __attribute__((ext_vector_type(4)));

static __device__ __forceinline__ float san(float x, float lo, float hi){
    return fminf(fmaxf(x, lo), hi);
}

static __device__ __forceinline__ float dot2acc(half2v a, half2v b, float c){
#if __has_builtin(__builtin_amdgcn_fdot2)
    return __builtin_amdgcn_fdot2(a, b, c, false);
#else
    return c + (float)a.x*(float)b.x + (float)a.y*(float)b.y;
#endif
}

// ================= K1: fused prep (cpr tables + full Xt unfold) =================
// blocks [0,nc): c'_p filter -> parity-split bf16 hi/lo tables
// blocks [nc,..): unfold pose -> Xt (bf16, transposed [col][j]) for ALL 3136 cols
__global__ void k_prep(const float* __restrict__ fw, const float* __restrict__ pose,
                       ushort* __restrict__ cpr, float* __restrict__ csum,
                       __hip_bfloat16* __restrict__ Xt, int nc)
{
    if ((int)blockIdx.x < nc){
        int id = (int)blockIdx.x*256 + threadIdx.x;
        if (id >= 16*288) return;
        int p = id / 288, m = id % 288;
        // c2r irfft ignores imag of DC/Nyquist bins; ortho norms cancel to 1/N
        float acc = fw[(0*16 + p)*2 + 0];
        for (int k = 1; k <= 143; ++k){
            float re = fw[(k*16 + p)*2 + 0];
            float im = fw[(k*16 + p)*2 + 1];
            int km = (k*m) % 288;
            float ang = 0.021816615649929116f * (float)km;  // 2*pi/288
            float s, c; __sincosf(ang, &s, &c);             // err ~1e-7 << bf16 table quant
            acc += 2.0f*(re*c - im*s);
        }
        float re144 = fw[(144*16 + p)*2 + 0];
        acc += re144 * ((m & 1) ? -1.0f : 1.0f);
        float cv = acc * (1.0f/288.0f);
        if (m == 0) cv += 1.0f;                            // + identity (residual)
        cv = san(cv, -1e4f, 1e4f);

        __hip_bfloat16 hb = __float2bfloat16(cv);
        float hif = __bfloat162float(hb);
        __hip_bfloat16 lb = __float2bfloat16(cv - hif);
        ushort hi = *(ushort*)&hb, lo = *(ushort*)&lb;

        ushort* c0h = cpr + p*592;
        ushort* c1h = cpr + 16*592   + p*592;
        ushort* c0l = cpr + 16*592*2 + p*592;
        ushort* c1l = cpr + 16*592*3 + p*592;
        int x1 = 288 - m;                       // covers cpr0[1..288], cpr1[0..287]
        c0h[x1] = hi;  c0l[x1] = lo;
        c1h[x1-1] = hi; c1l[x1-1] = lo;
        if (m >= 1){                            // covers cpr0[289..575], cpr1[288..574]
            int x2 = 576 - m;
            c0h[x2] = hi;  c0l[x2] = lo;
            c1h[x2-1] = hi; c1l[x2-1] = lo;
        } else {                                // cpr0[0] = cpr_ext[0] = c'[0]
            c0h[0] = hi; c0l[0] = lo;
            csum[p] = san(1.0f + fw[(0*16 + p)*2 + 0], -1e4f, 1e4f);
        }
        return;
    }
    int id = ((int)blockIdx.x - nc)*256 + threadIdx.x;
    if (id >= NCOLS*KKA_) return;
    int c = id / KKA_, j = id % KKA_;
    int n = c >> 4, q = c & 15;
    int bs = n / L_, l = n % L_, oy = l / OH_, ox = l % OH_;
    int kk = j >> 5, a = j & 31;
    int y = oy*2 - 1 + kk/3, x = ox*2 - 1 + kk%3;
    float v = 0.f;
    if ((unsigned)y < 14u && (unsigned)x < 14u)
        v = pose[((bs*(A_*PS) + a*PS + q)*14 + y)*14 + x];
    Xt[id] = __float2bfloat16(san(v, -1e4f, 1e4f));
}

// ================= K2: MEGA — per-site MFMA GEMM + v + 3 fused EM iterations =================
// One block per site. The site's GEMM U_p = (I+C_p)@X[:,16 cols] runs in-block
// (MFMA, 16-i chunks through an 8.4 KB LDS staging tile 'us'), v is computed
// chunk-by-chunk into v_lds (i<144, lane-indexed private columns) / v_h regs
// (i>=144, constant-indexed). U never touches global memory. Iterations 2-3 use
// the round-9 proven structure (16-i chunks, d_s+rbuf, 2 barriers/chunk).
__launch_bounds__(512, 1)
__global__ void
k_mega(const ushort* __restrict__ cpr, const __hip_bfloat16* __restrict__ Xt,
       const float* __restrict__ a_in,
       const float* __restrict__ mpw, const float* __restrict__ mpb,
       const float* __restrict__ csum,
       const float* __restrict__ beta_u, const float* __restrict__ beta_a,
       float* __restrict__ out)
{
    const int nl = blockIdx.x;          // site
    const int t = threadIdx.x;          // 512
    const int Bc = t >> 4, p = t & 15;  // EM thread = (Bc, p)
    const int bs = nl / L_, l = nl % L_;

    __shared__ uint      v_lds[72][512];   // 147456 B: v pairs i<144, [pair][t]
    __shared__ _Float16  us[16*264];       // 8448 B: GEMM chunk, us[p*264 + il*16 + q]
    __shared__ float     a_s[KKA_];        // 1152 B
    __shared__ float     d_s[16][33];      // 2112 B
    __shared__ float     rbuf[16][33];     // 2112 B
    __shared__ float     cst[32];          // 128 B   => 161,408 B total

    // unfold this site's activation row
    for (int j = t; j < KKA_; j += 512){
        int kk = j >> 5, a = j & 31;
        int oy = l / OH_, ox = l % OH_;
        int y = oy*2 - 1 + kk/3, x = ox*2 - 1 + kk%3;
        float v = 0.f;
        if ((unsigned)y < 14u && (unsigned)x < 14u)
            v = a_in[((bs*A_ + a)*14 + y)*14 + x];
        a_s[j] = san(v, 0.f, 1e4f);
    }
    // per-thread weight row as packed fp16
    half2v w_h[8];
    #pragma unroll
    for (int k = 0; k < 8; ++k){
        w_h[k].x = (_Float16)mpw[t*16 + 2*k];
        w_h[k].y = (_Float16)mpw[t*16 + 2*k + 1];
    }
    const float vb = mpb[t] * csum[p];  // bias pushed through the filter
    const float bu = beta_u[Bc];
    const float ba = beta_a[Bc];
    __syncthreads();                    // a_s ready

    float S0tot = 0.f;
    for (int j = 0; j < KKA_; ++j) S0tot += a_s[j];   // broadcast reads

    // ---- GEMM lane mapping: wave w handles p_g in {2w, 2w+1} ----
    const int w = t >> 6, lane = t & 63;
    const int mn = lane & 15, quad = lane >> 4;
    const int p0 = w*2;
    const __hip_bfloat16* xrow = Xt + (nl*16 + mn)*KKA_ + quad*8;

    float S1 = 0.f, S2 = 0.f;
    half2v v_h[72];

    // ---- phase 1: 18 chunks of 16 i: GEMM -> us -> v -> v_lds / v_h + moments ----
    // chunks 0..8 (v -> LDS), runtime loop
    for (int ch = 0; ch < 9; ++ch){
        floatx4 accA = {0,0,0,0}, accB = {0,0,0,0};
        for (int k0i = 0; k0i < 9; ++k0i){
            const int k0 = k0i*32;
            short8 bfrag = *(const short8*)&xrow[k0];
            #pragma unroll
            for (int pp = 0; pp < 2; ++pp){
                const int pg = p0 + pp;
                int o = 288 + k0 + quad*8 - (ch*16 + mn);
                int sel = o & 1, off = o - sel;
                const ushort* bh = cpr + (sel ? 16*592 : 0) + pg*592;
                const ushort* bl = cpr + 16*592*2 + (sel ? 16*592 : 0) + pg*592;
                short8 ah = *(const short8*)&bh[off];
                short8 al = *(const short8*)&bl[off];
                floatx4 acc = pp ? accB : accA;
                acc = __builtin_amdgcn_mfma_f32_16x16x32_bf16(ah, bfrag, acc, 0, 0, 0);
                acc = __builtin_amdgcn_mfma_f32_16x16x32_bf16(al, bfrag, acc, 0, 0, 0);
                if (pp) accB = acc; else accA = acc;
            }
        }
        #pragma unroll
        for (int r = 0; r < 4; ++r){
            us[p0*264     + (quad*4 + r)*16 + mn] = (_Float16)accA[r];
            us[(p0+1)*264 + (quad*4 + r)*16 + mn] = (_Float16)accB[r];
        }
        __syncthreads();                         // us chunk ready
        const _Float16* urow = &us[p*264];
        #pragma unroll
        for (int s = 0; s < 8; ++s){
            const int i0 = ch*16 + 2*s;
            union { uint4 u4; half2v h2[4]; } A0, A1, B0, B1;
            A0.u4 = *(const uint4*)&urow[(2*s)*16];
            A1.u4 = *(const uint4*)&urow[(2*s)*16 + 8];
            B0.u4 = *(const uint4*)&urow[(2*s+1)*16];
            B1.u4 = *(const uint4*)&urow[(2*s+1)*16 + 8];
            float v0 = vb, v1 = vb;
            #pragma unroll
            for (int m = 0; m < 4; ++m){
                v0 = dot2acc(A0.h2[m], w_h[m],   v0);
                v0 = dot2acc(A1.h2[m], w_h[4+m], v0);
                v1 = dot2acc(B0.h2[m], w_h[m],   v1);
                v1 = dot2acc(B1.h2[m], w_h[4+m], v1);
            }
            const float a0 = a_s[i0], a1 = a_s[i0+1];
            S1 += a0*v0 + a1*v1;
            S2 += a0*v0*v0 + a1*v1*v1;
            union { half2v h; uint u; } cv;
            cv.h.x = (_Float16)v0; cv.h.y = (_Float16)v1;
            v_lds[ch*8 + s][t] = cv.u;
        }
        __syncthreads();                         // us reads done before overwrite
    }
    // chunks 9..17 (v -> regs), fully unrolled for constant v_h indices
    #pragma unroll
    for (int c2 = 0; c2 < 9; ++c2){
        const int ch = 9 + c2;
        floatx4 accA = {0,0,0,0}, accB = {0,0,0,0};
        for (int k0i = 0; k0i < 9; ++k0i){
            const int k0 = k0i*32;
            short8 bfrag = *(const short8*)&xrow[k0];
            #pragma unroll
            for (int pp = 0; pp < 2; ++pp){
                const int pg = p0 + pp;
                int o = 288 + k0 + quad*8 - (ch*16 + mn);
                int sel = o & 1, off = o - sel;
                const ushort* bh = cpr + (sel ? 16*592 : 0) + pg*592;
                const ushort* bl = cpr + 16*592*2 + (sel ? 16*592 : 0) + pg*592;
                short8 ah = *(const short8*)&bh[off];
                short8 al = *(const short8*)&bl[off];
                floatx4 acc = pp ? accB : accA;
                acc = __builtin_amdgcn_mfma_f32_16x16x32_bf16(ah, bfrag, acc, 0, 0, 0);
                acc = __builtin_amdgcn_mfma_f32_16x16x32_bf16(al, bfrag, acc, 0, 0, 0);
                if (pp) accB = acc; else accA = acc;
            }
        }
        #pragma unroll
        for (int r = 0; r < 4; ++r){
            us[p0*264     + (quad*4 + r)*16 + mn] = (_Float16)accA[r];
            us[(p0+1)*264 + (quad*4 + r)*16 + mn] = (_Float16)accB[r];
        }
        __syncthreads();
        const _Float16* urow = &us[p*264];
        #pragma unroll
        for (int s = 0; s < 8; ++s){
            const int i0 = ch*16 + 2*s;
            union { uint4 u4; half2v h2[4]; } A0, A1, B0, B1;
            A0.u4 = *(const uint4*)&urow[(2*s)*16];
            A1.u4 = *(const uint4*)&urow[(2*s)*16 + 8];
            B0.u4 = *(const uint4*)&urow[(2*s+1)*16];
            B1.u4 = *(const uint4*)&urow[(2*s+1)*16 + 8];
            float v0 = vb, v1 = vb;
            #pragma unroll
            for (int m = 0; m < 4; ++m){
                v0 = dot2acc(A0.h2[m], w_h[m],   v0);
                v0 = dot2acc(A1.h2[m], w_h[4+m], v0);
                v1 = dot2acc(B0.h2[m], w_h[m],   v1);
                v1 = dot2acc(B1.h2[m], w_h[4+m], v1);
            }
            const float a0 = a_s[i0], a1 = a_s[i0+1];
            S1 += a0*v0 + a1*v1;
            S2 += a0*v0*v0 + a1*v1*v1;
            half2v vh; vh.x = (_Float16)v0; vh.y = (_Float16)v1;
            v_h[c2*8 + s] = vh;
        }
        __syncthreads();
    }

    // iter-1 m-step (r = 1/32 exactly); mu/i2s live in registers
    float mu_r, i2s_r;
    {
        const float rs  = S0tot * (1.0f/32.0f);
        const float inv = 1.0f / (rs + 1e-12f);
        const float S1r = S1 * (1.0f/32.0f), S2r = S2 * (1.0f/32.0f);
        mu_r = S1r * inv;
        const float sg  = fmaxf((S2r - 2.f*mu_r*S1r + mu_r*mu_r*rs) * inv, 0.f) + 1e-12f;
        i2s_r = 0.5f / sg;
        const float lg  = logf(sg);
        float cs = (bu + 0.5f*lg) * rs;
        float ls = lg + LOG_LN2PI;
        #pragma unroll
        for (int m = 1; m < 16; m <<= 1){ cs += __shfl_xor(cs, m, 16); ls += __shfl_xor(ls, m, 16); }
        const float aout = san(1.f/(1.f + expf(-LAM1*(ba - cs))), 1e-30f, 1.f);
        if (p == 0) cst[Bc] = logf(aout) - 0.5f*ls;
    }
    __syncthreads();

    // ---- iterations 2,3: round-9 structure (16-i chunks, 2 barriers each) ----
    const int b0 = p & 1, b1 = (p>>1)&1, b2 = (p>>2)&1, b3 = (p>>3)&1;
    float muF = 0.f, aF = 0.f;
    for (int it = 0; it < 2; ++it){
        const float lam = it ? LAM3 : LAM2;
        float T0 = 0.f, T1 = 0.f, T2 = 0.f;

        auto process = [&](int ibase, auto getpair){
            float e1[8], e2[4], e3[2], dfin;
            #pragma unroll
            for (int s = 0; s < 8; ++s){
                float v0, v1; getpair(s, v0, v1);
                float d0 = v0 - mu_r, d1 = v1 - mu_r;
                float ea = d0*d0*i2s_r, eb = d1*d1*i2s_r;
                float aown  = b0 ? eb : ea;
                float asend = b0 ? ea : eb;
                e1[s] = aown + __shfl_xor(asend, 1);
            }
            #pragma unroll
            for (int s = 0; s < 4; ++s){
                float aown  = b1 ? e1[2*s+1] : e1[2*s];
                float asend = b1 ? e1[2*s]   : e1[2*s+1];
                e2[s] = aown + __shfl_xor(asend, 2);
            }
            #pragma unroll
            for (int s = 0; s < 2; ++s){
                float aown  = b2 ? e2[2*s+1] : e2[2*s];
                float asend = b2 ? e2[2*s]   : e2[2*s+1];
                e3[s] = aown + __shfl_xor(asend, 4);
            }
            {
                float aown  = b3 ? e3[1] : e3[0];
                float asend = b3 ? e3[0] : e3[1];
                dfin = aown + __shfl_xor(asend, 8);
            }
            d_s[p][Bc] = dfin;                 // lane p holds d(i = ibase+p)
            __syncthreads();                   // (1) d_s ready
            {   // e-step softmax over B: thread -> (isub, Bce)
                const int isub = t >> 5, Bce = t & 31;
                float lnap = cst[Bce] - d_s[isub][Bce];
                float mx = lnap;
                #pragma unroll
                for (int m = 16; m >= 1; m >>= 1) mx = fmaxf(mx, __shfl_xor(mx, m));
                float ex = expf(lnap - mx);
                float sm = ex;
                #pragma unroll
                for (int m = 16; m >= 1; m >>= 1) sm += __shfl_xor(sm, m);
                rbuf[isub][Bce] = (ex / sm) * a_s[ibase + isub];
            }
            __syncthreads();                   // (2) rbuf ready
            #pragma unroll
            for (int s = 0; s < 8; ++s){
                float v0, v1; getpair(s, v0, v1);
                float r0 = rbuf[2*s][Bc], r1 = rbuf[2*s+1][Bc];
                T0 += r0 + r1;
                T1 += r0*v0 + r1*v1;
                T2 += r0*v0*v0 + r1*v1*v1;
            }
        };

        for (int ch = 0; ch < 9; ++ch){        // LDS half
            process(ch*16, [&](int s, float& v0, float& v1){
                union { uint u; half2v h; } cv; cv.u = v_lds[ch*8 + s][t];
                v0 = (float)cv.h.x; v1 = (float)cv.h.y;
            });
        }
        #pragma unroll
        for (int ch = 0; ch < 9; ++ch){        // register half (constant indices)
            process(144 + ch*16, [&](int s, float& v0, float& v1){
                half2v vh = v_h[ch*8 + s];
                v0 = (float)vh.x; v1 = (float)vh.y;
            });
        }

        // m-step
        const float inv = 1.f/(T0 + 1e-12f);
        const float mu  = T1 * inv;
        const float sg  = fmaxf((T2 - 2.f*mu*T1 + mu*mu*T0) * inv, 0.f) + 1e-12f;
        const float lg  = logf(sg);
        float cs = (bu + 0.5f*lg) * T0;
        float ls = lg + LOG_LN2PI;
        #pragma unroll
        for (int m = 1; m < 16; m <<= 1){ cs += __shfl_xor(cs, m, 16); ls += __shfl_xor(ls, m, 16); }
        const float aout = san(1.f/(1.f + expf(-lam*(ba - cs))), 1e-30f, 1.f);
        if (it == 0){
            mu_r = mu; i2s_r = 0.5f/sg;
            if (p == 0) cst[Bc] = logf(aout) - 0.5f*ls;
            __syncthreads();                   // cst visible before next softmax
        } else { muF = mu; aF = aout; }
    }

    // ---- outputs (fp32): [a_fin 4*32*49][pose_out 4*512*49] ----
    if (p == 0) out[bs*(B_*L_) + Bc*L_ + l] = san(aF, 0.f, 1.f);
    out[6272 + (bs*512 + t)*L_ + l] = san(muF, -1e4f, 1e4f);
}

// ================= launch =================
extern "C" void kernel_launch(void* const* d_in, const int* in_sizes, int n_in,
                              void* d_out, int out_size, void* d_ws, size_t ws_size,
                              hipStream_t stream)
{
    // ALL device tensors are float32 (reference is jnp.float32 end-to-end).
    const float* a_in   = (const float*)d_in[0];
    const float* pose   = (const float*)d_in[1];
    const float* mpw    = (const float*)d_in[2];
    const float* mpb    = (const float*)d_in[3];
    const float* fw     = (const float*)d_in[4];
    // d_in[5..8] (ln_g, ln_b, spat_w, spat_bias) are provably dead: softmax over B of a
    // B-independent gate is exactly 1/B regardless of their values.
    const float* beta_u = (const float*)d_in[9];
    const float* beta_a = (const float*)d_in[10];
    float* out = (float*)d_out;

    // ---- ws layout (byte offsets) ----
    // csum [16] f32         @ 0      (64 B)
    // cpr  4x[16][592] u16  @ 256    (75776 B)
    // Xt   [3136][288] bf16 @ 76288  (1806336 B)   -> total 1.88 MB
    char* base = (char*)d_ws;
    float*  csum = (float*)(base + 0);
    ushort* cpr  = (ushort*)(base + 256);
    __hip_bfloat16* Xt = (__hip_bfloat16*)(base + 76288);

    const int nc = 18;
    const int nx = (NCOLS*KKA_ + 255)/256;   // 3528
    k_prep<<<nc + nx, 256, 0, stream>>>(fw, pose, cpr, csum, Xt, nc);
    k_mega<<<NSITE, 512, 0, stream>>>(cpr, Xt, a_in, mpw, mpb, csum, beta_u, beta_a, out);
}